// Round 10
// baseline (414.454 us; speedup 1.0000x reference)
//
#include <hip/hip_runtime.h>
#include <math.h>

#define E_TOTAL 20000
#define G 32           // edges per block (2 MFMA edge-groups)
#define BLK 512        // 8 waves
#define NB 64
#define HID 128
#define MULD 1536

typedef float f32x4 __attribute__((ext_vector_type(4)));
typedef short bf16x8 __attribute__((ext_vector_type(8)));

static __device__ __forceinline__ unsigned short f2bf(float f) {
    unsigned int u = __float_as_uint(f);
    unsigned int r = u + 0x7FFFu + ((u >> 16) & 1u);
    return (unsigned short)(r >> 16);
}
static __device__ __forceinline__ float bf2f(unsigned short h) {
    return __uint_as_float(((unsigned int)h) << 16);
}

// ---------------- prep: W2 [128][1536] fp32 -> swizzled hi/lo bf16 ----------------
// slot layout: flat index i = ((ntg*4 + kk)*64 + lane)*8 + j
// content: W2t[n = ntg*16 + (lane&15)][k = kk*32 + (lane>>4)*8 + j] = W2[k][n]
__global__ __launch_bounds__(256) void prep_w2s(const float* __restrict__ W2,
                                                unsigned short* __restrict__ hi,
                                                unsigned short* __restrict__ lo) {
    const int i = blockIdx.x * 256 + threadIdx.x;   // 0 .. 196607
    const int j    = i & 7;
    const int lane = (i >> 3) & 63;
    const int kk   = (i >> 9) & 3;
    const int ntg  = i >> 11;                        // 0..95
    const int k = kk*32 + (lane >> 4)*8 + j;
    const int n = ntg*16 + (lane & 15);
    const float f = W2[k * MULD + n];
    const unsigned short h = f2bf(f);
    hi[i] = h;
    lo[i] = f2bf(f - bf2f(h));
}

// ---------------- main fused kernel ----------------
__global__ __launch_bounds__(BLK, 4) void fused_tp_kernel(
    const float* __restrict__ r,
    const float* __restrict__ W1,
    const float* __restrict__ b1,
    const unsigned short* __restrict__ w2hs,  // swizzled hi
    const unsigned short* __restrict__ w2ls,  // swizzled lo
    const float* __restrict__ b2,
    const float* __restrict__ wl0,
    const float* __restrict__ wl1,
    float* __restrict__ out)
{
    __shared__ __align__(16) float s_h[G][132];     // h fp32, padded
    __shared__ __align__(16) float s_basis[G][NB];
    __shared__ float s_Y1[G][3];
    __shared__ float s_A1[G][9];
    __shared__ float s_A2[G][9];
    __shared__ float s_rad[G];
    __shared__ int   s_mask[G];

    const int t  = threadIdx.x;
    const int e0 = blockIdx.x * G;
    const int w  = t >> 6;        // wave id 0..7
    const int l  = t & 63;
    const int lr = l & 15;
    const int lq = l >> 4;

    // ---------------- Phase A: geometry ----------------
    if (t < G) {
        const int e = e0 + t;
        float rx = r[e*3+0], ry = r[e*3+1], rz = r[e*3+2];
        float rad = sqrtf(rx*rx + ry*ry + rz*rz);
        s_rad[t]  = rad;
        s_mask[t] = (rad > 0.0f) ? 1 : 0;
        float inv = 1.0f / fmaxf(rad, 1e-12f);
        float x = rx*inv, y = ry*inv, z = rz*inv;

        const float SQ3  = 1.7320508075688772f;
        const float SQ15 = 3.872983346207417f;
        float Y10 = SQ3*y, Y11 = SQ3*z, Y12 = SQ3*x;
        s_Y1[t][0]=Y10; s_Y1[t][1]=Y11; s_Y1[t][2]=Y12;

        float Y20 = SQ15*x*y;
        float Y21 = SQ15*y*z;
        float Y22 = 1.118033988749895f*(3.f*z*z - 1.f);
        float Y23 = SQ15*z*x;
        float Y24 = 1.9364916731037085f*(x*x - y*y);

        const float n1  = 0.21650635094610965f;  // sqrt(3)/8
        const float r6  = 0.4082482904638631f;
        const float cA1 = n1 * r6;
        s_A1[t][0] = 0.0f;      s_A1[t][1] =  cA1*Y12; s_A1[t][2] = -cA1*Y11;
        s_A1[t][3] = -cA1*Y12;  s_A1[t][4] = 0.0f;     s_A1[t][5] =  cA1*Y10;
        s_A1[t][6] =  cA1*Y11;  s_A1[t][7] = -cA1*Y10; s_A1[t][8] = 0.0f;

        const float s2 = 0.7071067811865476f;
        float M00 = -r6*Y22 + s2*Y24;
        float M01 =  s2*Y20;
        float M02 =  s2*Y23;
        float M11 = -r6*Y22 - s2*Y24;
        float M12 =  s2*Y21;
        float M22 =  2.0f*r6*Y22;
        const float c5 = n1 * 0.4472135954999579f;
        s_A2[t][0] = c5*M11; s_A2[t][1] = c5*M12; s_A2[t][2] = c5*M01;
        s_A2[t][3] = c5*M12; s_A2[t][4] = c5*M22; s_A2[t][5] = c5*M02;
        s_A2[t][6] = c5*M01; s_A2[t][7] = c5*M02; s_A2[t][8] = c5*M00;
    }
    __syncthreads();

    // ---------------- Phase B: RBF ----------------
    for (int idx = t; idx < G*NB; idx += BLK) {
        int g = idx >> 6, k = idx & 63;
        float rad = s_rad[g];
        float c = (3.0f * (float)k) * (1.0f/63.0f);
        float d = (rad - c) * (64.0f/3.0f);
        s_basis[g][k] = __expf(-d*d);
    }
    __syncthreads();

    // ---------------- Phase C: h = silu(basis@W1+b1), f32x4 per item ----------------
    for (int idx = t; idx < G*32; idx += BLK) {      // 1024 f32x4 items
        const int g  = idx >> 5;
        const int c0 = (idx & 31) * 4;
        f32x4 acc = *reinterpret_cast<const f32x4*>(&b1[c0]);
#pragma unroll 8
        for (int k = 0; k < NB; ++k) {
            const f32x4 wv = *reinterpret_cast<const f32x4*>(&W1[k*HID + c0]);
            const float bv = s_basis[g][k];
            acc.x = fmaf(bv, wv.x, acc.x);
            acc.y = fmaf(bv, wv.y, acc.y);
            acc.z = fmaf(bv, wv.z, acc.z);
            acc.w = fmaf(bv, wv.w, acc.w);
        }
        f32x4 res;
        res.x = acc.x / (1.0f + __expf(-acc.x));
        res.y = acc.y / (1.0f + __expf(-acc.y));
        res.z = acc.z / (1.0f + __expf(-acc.z));
        res.w = acc.w / (1.0f + __expf(-acc.w));
        *reinterpret_cast<f32x4*>(&s_h[g][c0]) = res;
    }
    __syncthreads();

    // ---------------- A-fragments (hi/lo bf16), two edge groups ----------------
    bf16x8 ah0[4], al0[4], ah1[4], al1[4];
    {
        auto build = [&](const float* hrow, bf16x8* ah, bf16x8* al) {
#pragma unroll
            for (int kk = 0; kk < 4; ++kk) {
                f32x4 v0 = *reinterpret_cast<const f32x4*>(&hrow[kk*32 + lq*8]);
                f32x4 v1 = *reinterpret_cast<const f32x4*>(&hrow[kk*32 + lq*8 + 4]);
                float hv[8] = {v0.x, v0.y, v0.z, v0.w, v1.x, v1.y, v1.z, v1.w};
                bf16x8 h8, l8;
#pragma unroll
                for (int j = 0; j < 8; ++j) {
                    unsigned short hb = f2bf(hv[j]);
                    float rem = hv[j] - bf2f(hb);
                    h8[j] = (short)hb;
                    l8[j] = (short)f2bf(rem);
                }
                ah[kk] = h8; al[kk] = l8;
            }
        };
        build(&s_h[lr][0],      ah0, al0);
        build(&s_h[16 + lr][0], ah1, al1);
    }

    const float c00 = 0.17677669529663687f;   // 1/sqrt(32)
    const float cTR = 0.10206207261596577f;   // c00/sqrt(3)
    const float cBL = 0.125f;
    const float cD  = 0.125f;

    const bf16x8* ph = reinterpret_cast<const bf16x8*>(w2hs);
    const bf16x8* pl = reinterpret_cast<const bf16x8*>(w2ls);

    // Both edge-groups' GEMM for one n-tile; B loaded once (contiguous 1KB/instr).
    // Lane holds D[edge = eg*16 + 4lq+rr][n-in-tile = lr]  (proven R4 layout)
    auto tile_gemm2 = [&](int ntg, f32x4& r0, f32x4& r1) {
        f32x4 a_hh{0.f,0.f,0.f,0.f}, a_hl{0.f,0.f,0.f,0.f}, a_lh{0.f,0.f,0.f,0.f};
        f32x4 b_hh{0.f,0.f,0.f,0.f}, b_hl{0.f,0.f,0.f,0.f}, b_lh{0.f,0.f,0.f,0.f};
#pragma unroll
        for (int kk = 0; kk < 4; ++kk) {
            const bf16x8 Bh = ph[(ntg*4 + kk)*64 + l];
            const bf16x8 Bl = pl[(ntg*4 + kk)*64 + l];
            a_hh = __builtin_amdgcn_mfma_f32_16x16x32_bf16(ah0[kk], Bh, a_hh, 0, 0, 0);
            a_hl = __builtin_amdgcn_mfma_f32_16x16x32_bf16(ah0[kk], Bl, a_hl, 0, 0, 0);
            a_lh = __builtin_amdgcn_mfma_f32_16x16x32_bf16(al0[kk], Bh, a_lh, 0, 0, 0);
            b_hh = __builtin_amdgcn_mfma_f32_16x16x32_bf16(ah1[kk], Bh, b_hh, 0, 0, 0);
            b_hl = __builtin_amdgcn_mfma_f32_16x16x32_bf16(ah1[kk], Bl, b_hl, 0, 0, 0);
            b_lh = __builtin_amdgcn_mfma_f32_16x16x32_bf16(al1[kk], Bh, b_lh, 0, 0, 0);
        }
        const float b2v = b2[ntg*16 + lr];
        r0 = (a_hh + a_hl) + a_lh;
        r1 = (b_hh + b_hl) + b_lh;
        r0.x += b2v; r0.y += b2v; r0.z += b2v; r0.w += b2v;
        r1.x += b2v; r1.y += b2v; r1.z += b2v; r1.w += b2v;
    };

    // proven R4 store bodies, edge = eg*16 + 4lq + rr
    auto store_single = [&](f32x4 acc, int p, int nt, int eg) {
        if (p == 0) {
#pragma unroll
            for (int rr = 0; rr < 4; ++rr) {
                int e = eg*16 + lq*4 + rr;
                out[(size_t)(e0+e)*4096 + nt*64 + lr] = c00 * acc[rr];
            }
        } else if (p == 1) {
#pragma unroll
            for (int rr = 0; rr < 4; ++rr) {
                int e = eg*16 + lq*4 + rr;
                float base = cBL * acc[rr];
#pragma unroll
                for (int a = 0; a < 3; ++a) {
                    out[(size_t)(e0+e)*4096 + (16 + nt*3 + a)*64 + lr] = base * s_Y1[e][a];
                }
            }
        } else {
#pragma unroll
            for (int rr = 0; rr < 4; ++rr) {
                int e = eg*16 + lq*4 + rr;
                float base = cTR * acc[rr];
#pragma unroll
                for (int b = 0; b < 3; ++b) {
                    out[(size_t)(e0+e)*4096 + nt*64 + 16 + lr*3 + b] = base * s_Y1[e][b];
                }
            }
        }
    };

    auto store_triple = [&](f32x4 a3, f32x4 a4, f32x4 a5, int o, int eg) {
#pragma unroll
        for (int rr = 0; rr < 4; ++rr) {
            int e = eg*16 + lq*4 + rr;
            const float* A1 = &s_A1[e][0];
            const float* A2 = &s_A2[e][0];
            float rv3 = cD * a3[rr], rv4 = a4[rr], rv5 = a5[rr];
            float* orow = &out[(size_t)(e0+e)*4096 + (16 + o*3)*64 + 16 + lr*3];
#pragma unroll
            for (int a = 0; a < 3; ++a) {
#pragma unroll
                for (int b = 0; b < 3; ++b) {
                    float v = fmaf(rv4, A1[a*3+b], rv5 * A2[a*3+b]);
                    if (a == b) v += rv3;
                    orow[a*64 + b] = v;
                }
            }
        }
    };

    // ---------------- singles: paths 0,1,2 (2 tiles of each per wave) ----------------
#pragma unroll
    for (int s = 0; s < 6; ++s) {
        const int item = w + 8*s;        // 0..47; ntg = item; p = item>>4; nt = item&15
        const int p  = item >> 4;
        const int nt = item & 15;
        f32x4 r0, r1;
        tile_gemm2(item, r0, r1);
        store_single(r0, p, nt, 0);
        store_single(r1, p, nt, 1);
    }

    // ---------------- triples: BR quadrant, paths 3+4+5 at same o ----------------
#pragma unroll
    for (int tt = 0; tt < 2; ++tt) {
        const int o = w + 8*tt;          // 0..15
        f32x4 a3_0, a3_1, a4_0, a4_1, a5_0, a5_1;
        tile_gemm2(48 + o, a3_0, a3_1);
        tile_gemm2(64 + o, a4_0, a4_1);
        tile_gemm2(80 + o, a5_0, a5_1);
        store_triple(a3_0, a4_0, a5_0, o, 0);
        store_triple(a3_1, a4_1, a5_1, o, 1);
    }

    // ---------------- fixup: masked edges get kernel2 ----------------
    bool any = false;
#pragma unroll
    for (int e = 0; e < G; ++e) any |= (s_mask[e] == 0);
    if (any) {
        __syncthreads();
        for (int idx = t; idx < G*1024; idx += BLK) {
            int e = idx >> 10;
            if (s_mask[e]) continue;
            int q = idx & 1023;
            int row = q >> 4, col = (q & 15) * 4;
            float v[4];
#pragma unroll
            for (int j = 0; j < 4; ++j) {
                int cl = col + j;
                float val = 0.0f;
                if (row < 16 && cl < 16) {
                    val = wl0[row*16 + cl] * 0.25f;
                } else if (row >= 16 && cl >= 16) {
                    int o = (row-16)/3, aa = (row-16)%3;
                    int i = (cl-16)/3,  bb = (cl-16)%3;
                    val = (aa == bb) ? wl1[o*16 + i] * 0.25f : 0.0f;
                }
                v[j] = val;
            }
            f32x4 pack = {v[0], v[1], v[2], v[3]};
            *reinterpret_cast<f32x4*>(&out[(size_t)(e0+e)*4096 + row*64 + col]) = pack;
        }
    }
}

extern "C" void kernel_launch(void* const* d_in, const int* in_sizes, int n_in,
                              void* d_out, int out_size, void* d_ws, size_t ws_size,
                              hipStream_t stream) {
    const float* r   = (const float*)d_in[0];
    const float* W1  = (const float*)d_in[1];
    const float* b1  = (const float*)d_in[2];
    const float* W2  = (const float*)d_in[3];
    const float* b2  = (const float*)d_in[4];
    const float* wl0 = (const float*)d_in[5];
    const float* wl1 = (const float*)d_in[6];
    float* out = (float*)d_out;

    unsigned short* w2hs = (unsigned short*)d_ws;                 // 196608 bf16
    unsigned short* w2ls = w2hs + (size_t)MULD * HID;             // 196608 bf16

    prep_w2s<<<(MULD * HID) / 256, 256, 0, stream>>>(W2, w2hs, w2ls);

    const int nblocks = E_TOTAL / G;   // 625
    fused_tp_kernel<<<nblocks, BLK, 0, stream>>>(r, W1, b1, w2hs, w2ls, b2, wl0, wl1, out);
}

// Round 11
// 132.414 us; speedup vs baseline: 3.1300x; 3.1300x over previous
//
#include <hip/hip_runtime.h>
#include <math.h>

#define E_TOTAL 20000
#define G 32           // edges per block (2 MFMA edge-groups)
#define BLK 512        // 8 waves
#define NB 64
#define HID 128
#define MULD 1536

typedef float f32x4 __attribute__((ext_vector_type(4)));
typedef short bf16x8 __attribute__((ext_vector_type(8)));

static __device__ __forceinline__ unsigned short f2bf(float f) {
    unsigned int u = __float_as_uint(f);
    unsigned int r = u + 0x7FFFu + ((u >> 16) & 1u);
    return (unsigned short)(r >> 16);
}
static __device__ __forceinline__ float bf2f(unsigned short h) {
    return __uint_as_float(((unsigned int)h) << 16);
}

// ---------------- prep: W2 [128][1536] fp32 -> swizzled hi/lo bf16 ----------------
// slot layout: flat index i = ((ntg*4 + kk)*64 + lane)*8 + j
// content: W2t[n = ntg*16 + (lane&15)][k = kk*32 + (lane>>4)*8 + j] = W2[k][n]
__global__ __launch_bounds__(256) void prep_w2s(const float* __restrict__ W2,
                                                unsigned short* __restrict__ hi,
                                                unsigned short* __restrict__ lo) {
    const int i = blockIdx.x * 256 + threadIdx.x;   // 0 .. 196607
    const int j    = i & 7;
    const int lane = (i >> 3) & 63;
    const int kk   = (i >> 9) & 3;
    const int ntg  = i >> 11;                        // 0..95
    const int k = kk*32 + (lane >> 4)*8 + j;
    const int n = ntg*16 + (lane & 15);
    const float f = W2[k * MULD + n];
    const unsigned short h = f2bf(f);
    hi[i] = h;
    lo[i] = f2bf(f - bf2f(h));
}

// ---------------- main fused kernel ----------------
__global__ __launch_bounds__(BLK) void fused_tp_kernel(
    const float* __restrict__ r,
    const float* __restrict__ W1,
    const float* __restrict__ b1,
    const unsigned short* __restrict__ w2hs,  // swizzled hi
    const unsigned short* __restrict__ w2ls,  // swizzled lo
    const float* __restrict__ b2,
    const float* __restrict__ wl0,
    const float* __restrict__ wl1,
    float* __restrict__ out)
{
    __shared__ __align__(16) float s_h[G][132];     // h fp32, padded
    __shared__ __align__(16) float s_basis[G][NB];
    __shared__ float s_Y1[G][3];
    __shared__ float s_A1[G][9];
    __shared__ float s_A2[G][9];
    __shared__ float s_rad[G];
    __shared__ int   s_mask[G];

    const int t  = threadIdx.x;
    const int e0 = blockIdx.x * G;
    const int w  = t >> 6;        // wave id 0..7
    const int l  = t & 63;
    const int lr = l & 15;
    const int lq = l >> 4;

    // ---------------- Phase A: geometry ----------------
    if (t < G) {
        const int e = e0 + t;
        float rx = r[e*3+0], ry = r[e*3+1], rz = r[e*3+2];
        float rad = sqrtf(rx*rx + ry*ry + rz*rz);
        s_rad[t]  = rad;
        s_mask[t] = (rad > 0.0f) ? 1 : 0;
        float inv = 1.0f / fmaxf(rad, 1e-12f);
        float x = rx*inv, y = ry*inv, z = rz*inv;

        const float SQ3  = 1.7320508075688772f;
        const float SQ15 = 3.872983346207417f;
        float Y10 = SQ3*y, Y11 = SQ3*z, Y12 = SQ3*x;
        s_Y1[t][0]=Y10; s_Y1[t][1]=Y11; s_Y1[t][2]=Y12;

        float Y20 = SQ15*x*y;
        float Y21 = SQ15*y*z;
        float Y22 = 1.118033988749895f*(3.f*z*z - 1.f);
        float Y23 = SQ15*z*x;
        float Y24 = 1.9364916731037085f*(x*x - y*y);

        const float n1  = 0.21650635094610965f;  // sqrt(3)/8
        const float r6  = 0.4082482904638631f;
        const float cA1 = n1 * r6;
        s_A1[t][0] = 0.0f;      s_A1[t][1] =  cA1*Y12; s_A1[t][2] = -cA1*Y11;
        s_A1[t][3] = -cA1*Y12;  s_A1[t][4] = 0.0f;     s_A1[t][5] =  cA1*Y10;
        s_A1[t][6] =  cA1*Y11;  s_A1[t][7] = -cA1*Y10; s_A1[t][8] = 0.0f;

        const float s2 = 0.7071067811865476f;
        float M00 = -r6*Y22 + s2*Y24;
        float M01 =  s2*Y20;
        float M02 =  s2*Y23;
        float M11 = -r6*Y22 - s2*Y24;
        float M12 =  s2*Y21;
        float M22 =  2.0f*r6*Y22;
        const float c5 = n1 * 0.4472135954999579f;
        s_A2[t][0] = c5*M11; s_A2[t][1] = c5*M12; s_A2[t][2] = c5*M01;
        s_A2[t][3] = c5*M12; s_A2[t][4] = c5*M22; s_A2[t][5] = c5*M02;
        s_A2[t][6] = c5*M01; s_A2[t][7] = c5*M02; s_A2[t][8] = c5*M00;
    }
    __syncthreads();

    // ---------------- Phase B: RBF ----------------
    for (int idx = t; idx < G*NB; idx += BLK) {
        int g = idx >> 6, k = idx & 63;
        float rad = s_rad[g];
        float c = (3.0f * (float)k) * (1.0f/63.0f);
        float d = (rad - c) * (64.0f/3.0f);
        s_basis[g][k] = __expf(-d*d);
    }
    __syncthreads();

    // ---------------- Phase C: h = silu(basis@W1+b1), f32x4 per item ----------------
    for (int idx = t; idx < G*32; idx += BLK) {      // 1024 f32x4 items
        const int g  = idx >> 5;
        const int c0 = (idx & 31) * 4;
        f32x4 acc = *reinterpret_cast<const f32x4*>(&b1[c0]);
#pragma unroll 8
        for (int k = 0; k < NB; ++k) {
            const f32x4 wv = *reinterpret_cast<const f32x4*>(&W1[k*HID + c0]);
            const float bv = s_basis[g][k];
            acc.x = fmaf(bv, wv.x, acc.x);
            acc.y = fmaf(bv, wv.y, acc.y);
            acc.z = fmaf(bv, wv.z, acc.z);
            acc.w = fmaf(bv, wv.w, acc.w);
        }
        f32x4 res;
        res.x = acc.x / (1.0f + __expf(-acc.x));
        res.y = acc.y / (1.0f + __expf(-acc.y));
        res.z = acc.z / (1.0f + __expf(-acc.z));
        res.w = acc.w / (1.0f + __expf(-acc.w));
        *reinterpret_cast<f32x4*>(&s_h[g][c0]) = res;
    }
    __syncthreads();

    // ---------------- A-fragments (hi/lo bf16), two edge groups ----------------
    bf16x8 ah0[4], al0[4], ah1[4], al1[4];
    {
        auto build = [&](const float* hrow, bf16x8* ah, bf16x8* al) {
#pragma unroll
            for (int kk = 0; kk < 4; ++kk) {
                f32x4 v0 = *reinterpret_cast<const f32x4*>(&hrow[kk*32 + lq*8]);
                f32x4 v1 = *reinterpret_cast<const f32x4*>(&hrow[kk*32 + lq*8 + 4]);
                float hv[8] = {v0.x, v0.y, v0.z, v0.w, v1.x, v1.y, v1.z, v1.w};
                bf16x8 h8, l8;
#pragma unroll
                for (int j = 0; j < 8; ++j) {
                    unsigned short hb = f2bf(hv[j]);
                    float rem = hv[j] - bf2f(hb);
                    h8[j] = (short)hb;
                    l8[j] = (short)f2bf(rem);
                }
                ah[kk] = h8; al[kk] = l8;
            }
        };
        build(&s_h[lr][0],      ah0, al0);
        build(&s_h[16 + lr][0], ah1, al1);
    }

    const float c00 = 0.17677669529663687f;   // 1/sqrt(32)
    const float cTR = 0.10206207261596577f;   // c00/sqrt(3)
    const float cBL = 0.125f;
    const float cD  = 0.125f;

    const bf16x8* ph = reinterpret_cast<const bf16x8*>(w2hs);
    const bf16x8* pl = reinterpret_cast<const bf16x8*>(w2ls);

    // Both edge-groups' GEMM for one n-tile; B loaded once (contiguous 1KB/instr).
    // Lane holds D[edge = eg*16 + 4lq+rr][n-in-tile = lr]  (proven R4 layout)
    auto tile_gemm2 = [&](int ntg, f32x4& r0, f32x4& r1) {
        f32x4 a_hh{0.f,0.f,0.f,0.f}, a_hl{0.f,0.f,0.f,0.f}, a_lh{0.f,0.f,0.f,0.f};
        f32x4 b_hh{0.f,0.f,0.f,0.f}, b_hl{0.f,0.f,0.f,0.f}, b_lh{0.f,0.f,0.f,0.f};
#pragma unroll
        for (int kk = 0; kk < 4; ++kk) {
            const bf16x8 Bh = ph[(ntg*4 + kk)*64 + l];
            const bf16x8 Bl = pl[(ntg*4 + kk)*64 + l];
            a_hh = __builtin_amdgcn_mfma_f32_16x16x32_bf16(ah0[kk], Bh, a_hh, 0, 0, 0);
            a_hl = __builtin_amdgcn_mfma_f32_16x16x32_bf16(ah0[kk], Bl, a_hl, 0, 0, 0);
            a_lh = __builtin_amdgcn_mfma_f32_16x16x32_bf16(al0[kk], Bh, a_lh, 0, 0, 0);
            b_hh = __builtin_amdgcn_mfma_f32_16x16x32_bf16(ah1[kk], Bh, b_hh, 0, 0, 0);
            b_hl = __builtin_amdgcn_mfma_f32_16x16x32_bf16(ah1[kk], Bl, b_hl, 0, 0, 0);
            b_lh = __builtin_amdgcn_mfma_f32_16x16x32_bf16(al1[kk], Bh, b_lh, 0, 0, 0);
        }
        const float b2v = b2[ntg*16 + lr];
        r0 = (a_hh + a_hl) + a_lh;
        r1 = (b_hh + b_hl) + b_lh;
        r0.x += b2v; r0.y += b2v; r0.z += b2v; r0.w += b2v;
        r1.x += b2v; r1.y += b2v; r1.z += b2v; r1.w += b2v;
    };

    // proven R4 store bodies, edge = eg*16 + 4lq + rr  (plain stores, no nt)
    auto store_single = [&](f32x4 acc, int p, int nt, int eg) {
        if (p == 0) {
#pragma unroll
            for (int rr = 0; rr < 4; ++rr) {
                int e = eg*16 + lq*4 + rr;
                out[(size_t)(e0+e)*4096 + nt*64 + lr] = c00 * acc[rr];
            }
        } else if (p == 1) {
#pragma unroll
            for (int rr = 0; rr < 4; ++rr) {
                int e = eg*16 + lq*4 + rr;
                float base = cBL * acc[rr];
#pragma unroll
                for (int a = 0; a < 3; ++a) {
                    out[(size_t)(e0+e)*4096 + (16 + nt*3 + a)*64 + lr] = base * s_Y1[e][a];
                }
            }
        } else {
#pragma unroll
            for (int rr = 0; rr < 4; ++rr) {
                int e = eg*16 + lq*4 + rr;
                float base = cTR * acc[rr];
#pragma unroll
                for (int b = 0; b < 3; ++b) {
                    out[(size_t)(e0+e)*4096 + nt*64 + 16 + lr*3 + b] = base * s_Y1[e][b];
                }
            }
        }
    };

    auto store_triple = [&](f32x4 a3, f32x4 a4, f32x4 a5, int o, int eg) {
#pragma unroll
        for (int rr = 0; rr < 4; ++rr) {
            int e = eg*16 + lq*4 + rr;
            const float* A1 = &s_A1[e][0];
            const float* A2 = &s_A2[e][0];
            float rv3 = cD * a3[rr], rv4 = a4[rr], rv5 = a5[rr];
            float* orow = &out[(size_t)(e0+e)*4096 + (16 + o*3)*64 + 16 + lr*3];
#pragma unroll
            for (int a = 0; a < 3; ++a) {
#pragma unroll
                for (int b = 0; b < 3; ++b) {
                    float v = fmaf(rv4, A1[a*3+b], rv5 * A2[a*3+b]);
                    if (a == b) v += rv3;
                    orow[a*64 + b] = v;
                }
            }
        }
    };

    // ---------------- singles: paths 0,1,2 (2 tiles of each per wave) ----------------
#pragma unroll
    for (int s = 0; s < 6; ++s) {
        const int item = w + 8*s;        // 0..47; ntg = item; p = item>>4; nt = item&15
        const int p  = item >> 4;
        const int nt = item & 15;
        f32x4 r0, r1;
        tile_gemm2(item, r0, r1);
        store_single(r0, p, nt, 0);
        store_single(r1, p, nt, 1);
    }

    // ---------------- triples: BR quadrant, paths 3+4+5 at same o ----------------
#pragma unroll
    for (int tt = 0; tt < 2; ++tt) {
        const int o = w + 8*tt;          // 0..15
        f32x4 a3_0, a3_1, a4_0, a4_1, a5_0, a5_1;
        tile_gemm2(48 + o, a3_0, a3_1);
        tile_gemm2(64 + o, a4_0, a4_1);
        tile_gemm2(80 + o, a5_0, a5_1);
        store_triple(a3_0, a4_0, a5_0, o, 0);
        store_triple(a3_1, a4_1, a5_1, o, 1);
    }

    // ---------------- fixup: masked edges get kernel2 ----------------
    bool any = false;
#pragma unroll
    for (int e = 0; e < G; ++e) any |= (s_mask[e] == 0);
    if (any) {
        __syncthreads();
        for (int idx = t; idx < G*1024; idx += BLK) {
            int e = idx >> 10;
            if (s_mask[e]) continue;
            int q = idx & 1023;
            int row = q >> 4, col = (q & 15) * 4;
            float v[4];
#pragma unroll
            for (int j = 0; j < 4; ++j) {
                int cl = col + j;
                float val = 0.0f;
                if (row < 16 && cl < 16) {
                    val = wl0[row*16 + cl] * 0.25f;
                } else if (row >= 16 && cl >= 16) {
                    int o = (row-16)/3, aa = (row-16)%3;
                    int i = (cl-16)/3,  bb = (cl-16)%3;
                    val = (aa == bb) ? wl1[o*16 + i] * 0.25f : 0.0f;
                }
                v[j] = val;
            }
            f32x4 pack = {v[0], v[1], v[2], v[3]};
            *reinterpret_cast<f32x4*>(&out[(size_t)(e0+e)*4096 + row*64 + col]) = pack;
        }
    }
}

extern "C" void kernel_launch(void* const* d_in, const int* in_sizes, int n_in,
                              void* d_out, int out_size, void* d_ws, size_t ws_size,
                              hipStream_t stream) {
    const float* r   = (const float*)d_in[0];
    const float* W1  = (const float*)d_in[1];
    const float* b1  = (const float*)d_in[2];
    const float* W2  = (const float*)d_in[3];
    const float* b2  = (const float*)d_in[4];
    const float* wl0 = (const float*)d_in[5];
    const float* wl1 = (const float*)d_in[6];
    float* out = (float*)d_out;

    unsigned short* w2hs = (unsigned short*)d_ws;                 // 196608 bf16
    unsigned short* w2ls = w2hs + (size_t)MULD * HID;             // 196608 bf16

    prep_w2s<<<(MULD * HID) / 256, 256, 0, stream>>>(W2, w2hs, w2ls);

    const int nblocks = E_TOTAL / G;   // 625
    fused_tp_kernel<<<nblocks, BLK, 0, stream>>>(r, W1, b1, w2hs, w2ls, b2, wl0, wl1, out);
}

// Round 12
// 117.113 us; speedup vs baseline: 3.5389x; 1.1306x over previous
//
#include <hip/hip_runtime.h>
#include <math.h>

#define E_TOTAL 20000
#define G 32           // edges per block (2 MFMA edge-groups)
#define BLK 512        // 8 waves
#define NB 64
#define HID 128
#define MULD 1536

typedef float f32x4 __attribute__((ext_vector_type(4)));
typedef short bf16x8 __attribute__((ext_vector_type(8)));

static __device__ __forceinline__ unsigned short f2bf(float f) {
    unsigned int u = __float_as_uint(f);
    unsigned int r = u + 0x7FFFu + ((u >> 16) & 1u);
    return (unsigned short)(r >> 16);
}
static __device__ __forceinline__ float bf2f(unsigned short h) {
    return __uint_as_float(((unsigned int)h) << 16);
}

// ---------------- prep: W2 [128][1536] fp32 -> swizzled hi/lo bf16 ----------------
// slot layout: flat index i = ((ntg*4 + kk)*64 + lane)*8 + j
// content: W2t[n = ntg*16 + (lane&15)][k = kk*32 + (lane>>4)*8 + j] = W2[k][n]
__global__ __launch_bounds__(256) void prep_w2s(const float* __restrict__ W2,
                                                unsigned short* __restrict__ hi,
                                                unsigned short* __restrict__ lo) {
    const int i = blockIdx.x * 256 + threadIdx.x;   // 0 .. 196607
    const int j    = i & 7;
    const int lane = (i >> 3) & 63;
    const int kk   = (i >> 9) & 3;
    const int ntg  = i >> 11;                        // 0..95
    const int k = kk*32 + (lane >> 4)*8 + j;
    const int n = ntg*16 + (lane & 15);
    const float f = W2[k * MULD + n];
    const unsigned short h = f2bf(f);
    hi[i] = h;
    lo[i] = f2bf(f - bf2f(h));
}

// ---------------- main fused kernel ----------------
__global__ __launch_bounds__(BLK) void fused_tp_kernel(
    const float* __restrict__ r,
    const float* __restrict__ W1,
    const float* __restrict__ b1,
    const unsigned short* __restrict__ w2hs,  // swizzled hi
    const unsigned short* __restrict__ w2ls,  // swizzled lo
    const float* __restrict__ b2,
    const float* __restrict__ wl0,
    const float* __restrict__ wl1,
    float* __restrict__ out)
{
    __shared__ __align__(16) float s_h[G][132];     // h fp32, padded
    __shared__ __align__(16) float s_basis[G][NB];
    __shared__ __align__(16) float s_b2[MULD];
    __shared__ float s_Y1[G][3];
    __shared__ float s_A1[G][9];
    __shared__ float s_A2[G][9];
    __shared__ float s_rad[G];
    __shared__ int   s_mask[G];

    const int t  = threadIdx.x;
    const int e0 = blockIdx.x * G;
    const int w  = t >> 6;        // wave id 0..7
    const int l  = t & 63;
    const int lr = l & 15;
    const int lq = l >> 4;

    // ---------------- Phase A: geometry ----------------
    if (t < G) {
        const int e = e0 + t;
        float rx = r[e*3+0], ry = r[e*3+1], rz = r[e*3+2];
        float rad = sqrtf(rx*rx + ry*ry + rz*rz);
        s_rad[t]  = rad;
        s_mask[t] = (rad > 0.0f) ? 1 : 0;
        float inv = 1.0f / fmaxf(rad, 1e-12f);
        float x = rx*inv, y = ry*inv, z = rz*inv;

        const float SQ3  = 1.7320508075688772f;
        const float SQ15 = 3.872983346207417f;
        float Y10 = SQ3*y, Y11 = SQ3*z, Y12 = SQ3*x;
        s_Y1[t][0]=Y10; s_Y1[t][1]=Y11; s_Y1[t][2]=Y12;

        float Y20 = SQ15*x*y;
        float Y21 = SQ15*y*z;
        float Y22 = 1.118033988749895f*(3.f*z*z - 1.f);
        float Y23 = SQ15*z*x;
        float Y24 = 1.9364916731037085f*(x*x - y*y);

        const float n1  = 0.21650635094610965f;  // sqrt(3)/8
        const float r6  = 0.4082482904638631f;
        const float cA1 = n1 * r6;
        s_A1[t][0] = 0.0f;      s_A1[t][1] =  cA1*Y12; s_A1[t][2] = -cA1*Y11;
        s_A1[t][3] = -cA1*Y12;  s_A1[t][4] = 0.0f;     s_A1[t][5] =  cA1*Y10;
        s_A1[t][6] =  cA1*Y11;  s_A1[t][7] = -cA1*Y10; s_A1[t][8] = 0.0f;

        const float s2 = 0.7071067811865476f;
        float M00 = -r6*Y22 + s2*Y24;
        float M01 =  s2*Y20;
        float M02 =  s2*Y23;
        float M11 = -r6*Y22 - s2*Y24;
        float M12 =  s2*Y21;
        float M22 =  2.0f*r6*Y22;
        const float c5 = n1 * 0.4472135954999579f;
        s_A2[t][0] = c5*M11; s_A2[t][1] = c5*M12; s_A2[t][2] = c5*M01;
        s_A2[t][3] = c5*M12; s_A2[t][4] = c5*M22; s_A2[t][5] = c5*M02;
        s_A2[t][6] = c5*M01; s_A2[t][7] = c5*M02; s_A2[t][8] = c5*M00;
    }
    __syncthreads();

    // ---------------- Phase B: RBF + b2 staging ----------------
    for (int idx = t; idx < G*NB; idx += BLK) {
        int g = idx >> 6, k = idx & 63;
        float rad = s_rad[g];
        float c = (3.0f * (float)k) * (1.0f/63.0f);
        float d = (rad - c) * (64.0f/3.0f);
        s_basis[g][k] = __expf(-d*d);
    }
    for (int idx = t; idx < MULD; idx += BLK) s_b2[idx] = b2[idx];
    __syncthreads();

    // ---------------- Phase C: h = silu(basis@W1+b1), f32x4 per item ----------------
    for (int idx = t; idx < G*32; idx += BLK) {      // 1024 f32x4 items
        const int g  = idx >> 5;
        const int c0 = (idx & 31) * 4;
        f32x4 acc = *reinterpret_cast<const f32x4*>(&b1[c0]);
#pragma unroll 8
        for (int k = 0; k < NB; ++k) {
            const f32x4 wv = *reinterpret_cast<const f32x4*>(&W1[k*HID + c0]);
            const float bv = s_basis[g][k];
            acc.x = fmaf(bv, wv.x, acc.x);
            acc.y = fmaf(bv, wv.y, acc.y);
            acc.z = fmaf(bv, wv.z, acc.z);
            acc.w = fmaf(bv, wv.w, acc.w);
        }
        f32x4 res;
        res.x = acc.x / (1.0f + __expf(-acc.x));
        res.y = acc.y / (1.0f + __expf(-acc.y));
        res.z = acc.z / (1.0f + __expf(-acc.z));
        res.w = acc.w / (1.0f + __expf(-acc.w));
        *reinterpret_cast<f32x4*>(&s_h[g][c0]) = res;
    }
    __syncthreads();

    // ---------------- A-fragments (hi/lo bf16), two edge groups ----------------
    bf16x8 ah0[4], al0[4], ah1[4], al1[4];
    {
        auto build = [&](const float* hrow, bf16x8* ah, bf16x8* al) {
#pragma unroll
            for (int kk = 0; kk < 4; ++kk) {
                f32x4 v0 = *reinterpret_cast<const f32x4*>(&hrow[kk*32 + lq*8]);
                f32x4 v1 = *reinterpret_cast<const f32x4*>(&hrow[kk*32 + lq*8 + 4]);
                float hv[8] = {v0.x, v0.y, v0.z, v0.w, v1.x, v1.y, v1.z, v1.w};
                bf16x8 h8, l8;
#pragma unroll
                for (int j = 0; j < 8; ++j) {
                    unsigned short hb = f2bf(hv[j]);
                    float rem = hv[j] - bf2f(hb);
                    h8[j] = (short)hb;
                    l8[j] = (short)f2bf(rem);
                }
                ah[kk] = h8; al[kk] = l8;
            }
        };
        build(&s_h[lr][0],      ah0, al0);
        build(&s_h[16 + lr][0], ah1, al1);
    }

    const float c00 = 0.17677669529663687f;   // 1/sqrt(32)
    const float cTR = 0.10206207261596577f;   // c00/sqrt(3)
    const float cBL = 0.125f;
    const float cD  = 0.125f;

    const bf16x8* ph = reinterpret_cast<const bf16x8*>(w2hs);
    const bf16x8* pl = reinterpret_cast<const bf16x8*>(w2ls);

    // proven R4/R8 store bodies, edge = eg*16 + 4lq + rr
    auto store_single = [&](f32x4 acc, int p, int nt, int eg) {
        if (p == 0) {
#pragma unroll
            for (int rr = 0; rr < 4; ++rr) {
                int e = eg*16 + lq*4 + rr;
                float v = c00 * acc[rr];
                __builtin_nontemporal_store(v, &out[(size_t)(e0+e)*4096 + nt*64 + lr]);
            }
        } else if (p == 1) {
#pragma unroll
            for (int rr = 0; rr < 4; ++rr) {
                int e = eg*16 + lq*4 + rr;
                float base = cBL * acc[rr];
#pragma unroll
                for (int a = 0; a < 3; ++a) {
                    float v = base * s_Y1[e][a];
                    __builtin_nontemporal_store(v, &out[(size_t)(e0+e)*4096 + (16 + nt*3 + a)*64 + lr]);
                }
            }
        } else {
#pragma unroll
            for (int rr = 0; rr < 4; ++rr) {
                int e = eg*16 + lq*4 + rr;
                float base = cTR * acc[rr];
#pragma unroll
                for (int b = 0; b < 3; ++b) {
                    float v = base * s_Y1[e][b];
                    __builtin_nontemporal_store(v, &out[(size_t)(e0+e)*4096 + nt*64 + 16 + lr*3 + b]);
                }
            }
        }
    };

    auto store_triple = [&](f32x4 a3, f32x4 a4, f32x4 a5, int o, int eg) {
#pragma unroll
        for (int rr = 0; rr < 4; ++rr) {
            int e = eg*16 + lq*4 + rr;
            const float* A1 = &s_A1[e][0];
            const float* A2 = &s_A2[e][0];
            float rv3 = cD * a3[rr], rv4 = a4[rr], rv5 = a5[rr];
            float* orow = &out[(size_t)(e0+e)*4096 + (16 + o*3)*64 + 16 + lr*3];
#pragma unroll
            for (int a = 0; a < 3; ++a) {
#pragma unroll
                for (int b = 0; b < 3; ++b) {
                    float v = fmaf(rv4, A1[a*3+b], rv5 * A2[a*3+b]);
                    if (a == b) v += rv3;
                    __builtin_nontemporal_store(v, &orow[a*64 + b]);
                }
            }
        }
    };

    // ---------------- pipelined item loop: 6 singles + 2 triple-groups ----------------
    // item order: singles {w,w+8,..,w+40}; triple grp1 {48+w,64+w,80+w} (o=w);
    //             triple grp2 {56+w,72+w,88+w} (o=w+8)
    const int items[12] = { w, w+8, w+16, w+24, w+32, w+40,
                            48+w, 64+w, 80+w, 56+w, 72+w, 88+w };

    bf16x8 B0h[4], B0l[4], B1h[4], B1l[4];
    auto loadB = [&](bf16x8* Bh, bf16x8* Bl, int ntg) {
#pragma unroll
        for (int kk = 0; kk < 4; ++kk) {
            Bh[kk] = ph[(ntg*4 + kk)*64 + l];
            Bl[kk] = pl[(ntg*4 + kk)*64 + l];
        }
    };
    // compute both egs for current buffered tile; bias-seeded chained accumulation
    auto mfma_item = [&](const bf16x8* Bh, const bf16x8* Bl, int ntg, f32x4& a0, f32x4& a1) {
        const float b2v = s_b2[ntg*16 + lr];
        a0 = f32x4{b2v, b2v, b2v, b2v};
        a1 = a0;
#pragma unroll
        for (int kk = 0; kk < 4; ++kk) {
            a0 = __builtin_amdgcn_mfma_f32_16x16x32_bf16(ah0[kk], Bh[kk], a0, 0, 0, 0);
            a1 = __builtin_amdgcn_mfma_f32_16x16x32_bf16(ah1[kk], Bh[kk], a1, 0, 0, 0);
            a0 = __builtin_amdgcn_mfma_f32_16x16x32_bf16(ah0[kk], Bl[kk], a0, 0, 0, 0);
            a1 = __builtin_amdgcn_mfma_f32_16x16x32_bf16(ah1[kk], Bl[kk], a1, 0, 0, 0);
            a0 = __builtin_amdgcn_mfma_f32_16x16x32_bf16(al0[kk], Bh[kk], a0, 0, 0, 0);
            a1 = __builtin_amdgcn_mfma_f32_16x16x32_bf16(al1[kk], Bh[kk], a1, 0, 0, 0);
        }
    };

    loadB(B0h, B0l, items[0]);
    f32x4 tri0[3], tri1[3];   // triple-group stash per eg

#pragma unroll
    for (int i = 0; i < 12; ++i) {
        bf16x8* curH = (i & 1) ? B1h : B0h;
        bf16x8* curL = (i & 1) ? B1l : B0l;
        bf16x8* nxtH = (i & 1) ? B0h : B1h;
        bf16x8* nxtL = (i & 1) ? B0l : B1l;
        if (i < 11) loadB(nxtH, nxtL, items[i+1]);   // prefetch next item

        f32x4 a0, a1;
        mfma_item(curH, curL, items[i], a0, a1);

        if (i < 6) {
            const int p  = items[i] >> 4;
            const int nt = items[i] & 15;
            store_single(a0, p, nt, 0);
            store_single(a1, p, nt, 1);
        } else {
            const int ti = (i - 6) % 3;
            tri0[ti] = a0; tri1[ti] = a1;
            if (ti == 2) {
                const int o = (i < 9) ? w : (w + 8);
                store_triple(tri0[0], tri0[1], tri0[2], o, 0);
                store_triple(tri1[0], tri1[1], tri1[2], o, 1);
            }
        }
    }

    // ---------------- fixup: masked edges get kernel2 ----------------
    bool any = false;
#pragma unroll
    for (int e = 0; e < G; ++e) any |= (s_mask[e] == 0);
    if (any) {
        __syncthreads();
        for (int idx = t; idx < G*1024; idx += BLK) {
            int e = idx >> 10;
            if (s_mask[e]) continue;
            int q = idx & 1023;
            int row = q >> 4, col = (q & 15) * 4;
            float v[4];
#pragma unroll
            for (int j = 0; j < 4; ++j) {
                int cl = col + j;
                float val = 0.0f;
                if (row < 16 && cl < 16) {
                    val = wl0[row*16 + cl] * 0.25f;
                } else if (row >= 16 && cl >= 16) {
                    int o = (row-16)/3, aa = (row-16)%3;
                    int i2 = (cl-16)/3, bb = (cl-16)%3;
                    val = (aa == bb) ? wl1[o*16 + i2] * 0.25f : 0.0f;
                }
                v[j] = val;
            }
            f32x4 pack = {v[0], v[1], v[2], v[3]};
            __builtin_nontemporal_store(pack,
                reinterpret_cast<f32x4*>(&out[(size_t)(e0+e)*4096 + row*64 + col]));
        }
    }
}

extern "C" void kernel_launch(void* const* d_in, const int* in_sizes, int n_in,
                              void* d_out, int out_size, void* d_ws, size_t ws_size,
                              hipStream_t stream) {
    const float* r   = (const float*)d_in[0];
    const float* W1  = (const float*)d_in[1];
    const float* b1  = (const float*)d_in[2];
    const float* W2  = (const float*)d_in[3];
    const float* b2  = (const float*)d_in[4];
    const float* wl0 = (const float*)d_in[5];
    const float* wl1 = (const float*)d_in[6];
    float* out = (float*)d_out;

    unsigned short* w2hs = (unsigned short*)d_ws;                 // 196608 bf16
    unsigned short* w2ls = w2hs + (size_t)MULD * HID;             // 196608 bf16

    prep_w2s<<<(MULD * HID) / 256, 256, 0, stream>>>(W2, w2hs, w2ls);

    const int nblocks = E_TOTAL / G;   // 625
    fused_tp_kernel<<<nblocks, BLK, 0, stream>>>(r, W1, b1, w2hs, w2ls, b2, wl0, wl1, out);
}

// Round 13
// 115.433 us; speedup vs baseline: 3.5904x; 1.0146x over previous
//
#include <hip/hip_runtime.h>
#include <math.h>

#define E_TOTAL 20000
#define G 32           // edges per block (2 MFMA edge-groups)
#define BLK 512        // 8 waves
#define NB 64
#define HID 128
#define MULD 1536

typedef float f32x4 __attribute__((ext_vector_type(4)));
typedef short bf16x8 __attribute__((ext_vector_type(8)));

struct f3_t { float x, y, z; };   // 12-byte store -> global_store_dwordx3

static __device__ __forceinline__ unsigned short f2bf(float f) {
    unsigned int u = __float_as_uint(f);
    unsigned int r = u + 0x7FFFu + ((u >> 16) & 1u);
    return (unsigned short)(r >> 16);
}
static __device__ __forceinline__ float bf2f(unsigned short h) {
    return __uint_as_float(((unsigned int)h) << 16);
}

// ---------------- prep: W2 [128][1536] fp32 -> swizzled hi/lo bf16 ----------------
// slot layout: flat index i = ((ntg*4 + kk)*64 + lane)*8 + j
// content: W2t[n = ntg*16 + (lane&15)][k = kk*32 + (lane>>4)*8 + j] = W2[k][n]
__global__ __launch_bounds__(256) void prep_w2s(const float* __restrict__ W2,
                                                unsigned short* __restrict__ hi,
                                                unsigned short* __restrict__ lo) {
    const int i = blockIdx.x * 256 + threadIdx.x;   // 0 .. 196607
    const int j    = i & 7;
    const int lane = (i >> 3) & 63;
    const int kk   = (i >> 9) & 3;
    const int ntg  = i >> 11;                        // 0..95
    const int k = kk*32 + (lane >> 4)*8 + j;
    const int n = ntg*16 + (lane & 15);
    const float f = W2[k * MULD + n];
    const unsigned short h = f2bf(f);
    hi[i] = h;
    lo[i] = f2bf(f - bf2f(h));
}

// ---------------- main fused kernel ----------------
__global__ __launch_bounds__(BLK) void fused_tp_kernel(
    const float* __restrict__ r,
    const float* __restrict__ W1,
    const float* __restrict__ b1,
    const unsigned short* __restrict__ w2hs,  // swizzled hi
    const unsigned short* __restrict__ w2ls,  // swizzled lo
    const float* __restrict__ b2,
    const float* __restrict__ wl0,
    const float* __restrict__ wl1,
    float* __restrict__ out)
{
    __shared__ __align__(16) float s_h[G][132];     // h fp32, padded
    __shared__ __align__(16) float s_basis[G][NB];
    __shared__ __align__(16) float s_b2[MULD];
    __shared__ float s_Y1[G][3];
    __shared__ float s_A1[G][9];
    __shared__ float s_A2[G][9];
    __shared__ float s_rad[G];
    __shared__ int   s_mask[G];

    const int t  = threadIdx.x;
    const int e0 = blockIdx.x * G;
    const int w  = t >> 6;        // wave id 0..7
    const int l  = t & 63;
    const int lr = l & 15;
    const int lq = l >> 4;

    // ---------------- Phase A: geometry ----------------
    if (t < G) {
        const int e = e0 + t;
        float rx = r[e*3+0], ry = r[e*3+1], rz = r[e*3+2];
        float rad = sqrtf(rx*rx + ry*ry + rz*rz);
        s_rad[t]  = rad;
        s_mask[t] = (rad > 0.0f) ? 1 : 0;
        float inv = 1.0f / fmaxf(rad, 1e-12f);
        float x = rx*inv, y = ry*inv, z = rz*inv;

        const float SQ3  = 1.7320508075688772f;
        const float SQ15 = 3.872983346207417f;
        float Y10 = SQ3*y, Y11 = SQ3*z, Y12 = SQ3*x;
        s_Y1[t][0]=Y10; s_Y1[t][1]=Y11; s_Y1[t][2]=Y12;

        float Y20 = SQ15*x*y;
        float Y21 = SQ15*y*z;
        float Y22 = 1.118033988749895f*(3.f*z*z - 1.f);
        float Y23 = SQ15*z*x;
        float Y24 = 1.9364916731037085f*(x*x - y*y);

        const float n1  = 0.21650635094610965f;  // sqrt(3)/8
        const float r6  = 0.4082482904638631f;
        const float cA1 = n1 * r6;
        s_A1[t][0] = 0.0f;      s_A1[t][1] =  cA1*Y12; s_A1[t][2] = -cA1*Y11;
        s_A1[t][3] = -cA1*Y12;  s_A1[t][4] = 0.0f;     s_A1[t][5] =  cA1*Y10;
        s_A1[t][6] =  cA1*Y11;  s_A1[t][7] = -cA1*Y10; s_A1[t][8] = 0.0f;

        const float s2 = 0.7071067811865476f;
        float M00 = -r6*Y22 + s2*Y24;
        float M01 =  s2*Y20;
        float M02 =  s2*Y23;
        float M11 = -r6*Y22 - s2*Y24;
        float M12 =  s2*Y21;
        float M22 =  2.0f*r6*Y22;
        const float c5 = n1 * 0.4472135954999579f;
        s_A2[t][0] = c5*M11; s_A2[t][1] = c5*M12; s_A2[t][2] = c5*M01;
        s_A2[t][3] = c5*M12; s_A2[t][4] = c5*M22; s_A2[t][5] = c5*M02;
        s_A2[t][6] = c5*M01; s_A2[t][7] = c5*M02; s_A2[t][8] = c5*M00;
    }
    __syncthreads();

    // ---------------- Phase B: RBF + b2 staging ----------------
    for (int idx = t; idx < G*NB; idx += BLK) {
        int g = idx >> 6, k = idx & 63;
        float rad = s_rad[g];
        float c = (3.0f * (float)k) * (1.0f/63.0f);
        float d = (rad - c) * (64.0f/3.0f);
        s_basis[g][k] = __expf(-d*d);
    }
    for (int idx = t; idx < MULD; idx += BLK) s_b2[idx] = b2[idx];
    __syncthreads();

    // ---------------- Phase C: h = silu(basis@W1+b1), f32x4 per item ----------------
    for (int idx = t; idx < G*32; idx += BLK) {      // 1024 f32x4 items
        const int g  = idx >> 5;
        const int c0 = (idx & 31) * 4;
        f32x4 acc = *reinterpret_cast<const f32x4*>(&b1[c0]);
#pragma unroll 8
        for (int k = 0; k < NB; ++k) {
            const f32x4 wv = *reinterpret_cast<const f32x4*>(&W1[k*HID + c0]);
            const float bv = s_basis[g][k];
            acc.x = fmaf(bv, wv.x, acc.x);
            acc.y = fmaf(bv, wv.y, acc.y);
            acc.z = fmaf(bv, wv.z, acc.z);
            acc.w = fmaf(bv, wv.w, acc.w);
        }
        f32x4 res;
        res.x = acc.x / (1.0f + __expf(-acc.x));
        res.y = acc.y / (1.0f + __expf(-acc.y));
        res.z = acc.z / (1.0f + __expf(-acc.z));
        res.w = acc.w / (1.0f + __expf(-acc.w));
        *reinterpret_cast<f32x4*>(&s_h[g][c0]) = res;
    }
    __syncthreads();

    // ---------------- A-fragments (hi/lo bf16), two edge groups ----------------
    bf16x8 ah0[4], al0[4], ah1[4], al1[4];
    {
        auto build = [&](const float* hrow, bf16x8* ah, bf16x8* al) {
#pragma unroll
            for (int kk = 0; kk < 4; ++kk) {
                f32x4 v0 = *reinterpret_cast<const f32x4*>(&hrow[kk*32 + lq*8]);
                f32x4 v1 = *reinterpret_cast<const f32x4*>(&hrow[kk*32 + lq*8 + 4]);
                float hv[8] = {v0.x, v0.y, v0.z, v0.w, v1.x, v1.y, v1.z, v1.w};
                bf16x8 h8, l8;
#pragma unroll
                for (int j = 0; j < 8; ++j) {
                    unsigned short hb = f2bf(hv[j]);
                    float rem = hv[j] - bf2f(hb);
                    h8[j] = (short)hb;
                    l8[j] = (short)f2bf(rem);
                }
                ah[kk] = h8; al[kk] = l8;
            }
        };
        build(&s_h[lr][0],      ah0, al0);
        build(&s_h[16 + lr][0], ah1, al1);
    }

    const float c00 = 0.17677669529663687f;   // 1/sqrt(32)
    const float cTR = 0.10206207261596577f;   // c00/sqrt(3)
    const float cBL = 0.125f;
    const float cD  = 0.125f;

    const bf16x8* ph = reinterpret_cast<const bf16x8*>(w2hs);
    const bf16x8* pl = reinterpret_cast<const bf16x8*>(w2ls);

    // proven R4/R8 store bodies, edge = eg*16 + 4lq + rr
    auto store_single = [&](f32x4 acc, int p, int nt, int eg) {
        if (p == 0) {
#pragma unroll
            for (int rr = 0; rr < 4; ++rr) {
                int e = eg*16 + lq*4 + rr;
                float v = c00 * acc[rr];
                __builtin_nontemporal_store(v, &out[(size_t)(e0+e)*4096 + nt*64 + lr]);
            }
        } else if (p == 1) {
#pragma unroll
            for (int rr = 0; rr < 4; ++rr) {
                int e = eg*16 + lq*4 + rr;
                float base = cBL * acc[rr];
#pragma unroll
                for (int a = 0; a < 3; ++a) {
                    float v = base * s_Y1[e][a];
                    __builtin_nontemporal_store(v, &out[(size_t)(e0+e)*4096 + (16 + nt*3 + a)*64 + lr]);
                }
            }
        } else {
            // TR: lane lr owns cols 16+3lr .. 16+3lr+2  -> one 12B store (full lines per instr)
#pragma unroll
            for (int rr = 0; rr < 4; ++rr) {
                int e = eg*16 + lq*4 + rr;
                float base = cTR * acc[rr];
                f3_t v = { base * s_Y1[e][0], base * s_Y1[e][1], base * s_Y1[e][2] };
                *reinterpret_cast<f3_t*>(&out[(size_t)(e0+e)*4096 + nt*64 + 16 + lr*3]) = v;
            }
        }
    };

    auto store_triple = [&](f32x4 a3, f32x4 a4, f32x4 a5, int o, int eg) {
#pragma unroll
        for (int rr = 0; rr < 4; ++rr) {
            int e = eg*16 + lq*4 + rr;
            const float* A1 = &s_A1[e][0];
            const float* A2 = &s_A2[e][0];
            float rv3 = cD * a3[rr], rv4 = a4[rr], rv5 = a5[rr];
            float* orow = &out[(size_t)(e0+e)*4096 + (16 + o*3)*64 + 16 + lr*3];
#pragma unroll
            for (int a = 0; a < 3; ++a) {
                f3_t v;
                float v0 = fmaf(rv4, A1[a*3+0], rv5 * A2[a*3+0]);
                float v1 = fmaf(rv4, A1[a*3+1], rv5 * A2[a*3+1]);
                float v2 = fmaf(rv4, A1[a*3+2], rv5 * A2[a*3+2]);
                if (a == 0) v0 += rv3;
                if (a == 1) v1 += rv3;
                if (a == 2) v2 += rv3;
                v.x = v0; v.y = v1; v.z = v2;
                *reinterpret_cast<f3_t*>(&orow[a*64]) = v;
            }
        }
    };

    // ---------------- pipelined item loop: 6 singles + 2 triple-groups ----------------
    const int items[12] = { w, w+8, w+16, w+24, w+32, w+40,
                            48+w, 64+w, 80+w, 56+w, 72+w, 88+w };

    bf16x8 B0h[4], B0l[4], B1h[4], B1l[4];
    auto loadB = [&](bf16x8* Bh, bf16x8* Bl, int ntg) {
#pragma unroll
        for (int kk = 0; kk < 4; ++kk) {
            Bh[kk] = ph[(ntg*4 + kk)*64 + l];
            Bl[kk] = pl[(ntg*4 + kk)*64 + l];
        }
    };
    auto mfma_item = [&](const bf16x8* Bh, const bf16x8* Bl, int ntg, f32x4& a0, f32x4& a1) {
        const float b2v = s_b2[ntg*16 + lr];
        a0 = f32x4{b2v, b2v, b2v, b2v};
        a1 = a0;
#pragma unroll
        for (int kk = 0; kk < 4; ++kk) {
            a0 = __builtin_amdgcn_mfma_f32_16x16x32_bf16(ah0[kk], Bh[kk], a0, 0, 0, 0);
            a1 = __builtin_amdgcn_mfma_f32_16x16x32_bf16(ah1[kk], Bh[kk], a1, 0, 0, 0);
            a0 = __builtin_amdgcn_mfma_f32_16x16x32_bf16(ah0[kk], Bl[kk], a0, 0, 0, 0);
            a1 = __builtin_amdgcn_mfma_f32_16x16x32_bf16(ah1[kk], Bl[kk], a1, 0, 0, 0);
            a0 = __builtin_amdgcn_mfma_f32_16x16x32_bf16(al0[kk], Bh[kk], a0, 0, 0, 0);
            a1 = __builtin_amdgcn_mfma_f32_16x16x32_bf16(al1[kk], Bh[kk], a1, 0, 0, 0);
        }
    };

    loadB(B0h, B0l, items[0]);
    f32x4 tri0[3], tri1[3];

#pragma unroll
    for (int i = 0; i < 12; ++i) {
        bf16x8* curH = (i & 1) ? B1h : B0h;
        bf16x8* curL = (i & 1) ? B1l : B0l;
        bf16x8* nxtH = (i & 1) ? B0h : B1h;
        bf16x8* nxtL = (i & 1) ? B0l : B1l;
        if (i < 11) loadB(nxtH, nxtL, items[i+1]);   // prefetch next item

        f32x4 a0, a1;
        mfma_item(curH, curL, items[i], a0, a1);

        if (i < 6) {
            const int p  = items[i] >> 4;
            const int nt = items[i] & 15;
            store_single(a0, p, nt, 0);
            store_single(a1, p, nt, 1);
        } else {
            const int ti = (i - 6) % 3;
            tri0[ti] = a0; tri1[ti] = a1;
            if (ti == 2) {
                const int o = (i < 9) ? w : (w + 8);
                store_triple(tri0[0], tri0[1], tri0[2], o, 0);
                store_triple(tri1[0], tri1[1], tri1[2], o, 1);
            }
        }
    }

    // ---------------- fixup: masked edges get kernel2 ----------------
    bool any = false;
#pragma unroll
    for (int e = 0; e < G; ++e) any |= (s_mask[e] == 0);
    if (any) {
        __syncthreads();
        for (int idx = t; idx < G*1024; idx += BLK) {
            int e = idx >> 10;
            if (s_mask[e]) continue;
            int q = idx & 1023;
            int row = q >> 4, col = (q & 15) * 4;
            float v[4];
#pragma unroll
            for (int j = 0; j < 4; ++j) {
                int cl = col + j;
                float val = 0.0f;
                if (row < 16 && cl < 16) {
                    val = wl0[row*16 + cl] * 0.25f;
                } else if (row >= 16 && cl >= 16) {
                    int o = (row-16)/3, aa = (row-16)%3;
                    int i2 = (cl-16)/3, bb = (cl-16)%3;
                    val = (aa == bb) ? wl1[o*16 + i2] * 0.25f : 0.0f;
                }
                v[j] = val;
            }
            f32x4 pack = {v[0], v[1], v[2], v[3]};
            __builtin_nontemporal_store(pack,
                reinterpret_cast<f32x4*>(&out[(size_t)(e0+e)*4096 + row*64 + col]));
        }
    }
}

extern "C" void kernel_launch(void* const* d_in, const int* in_sizes, int n_in,
                              void* d_out, int out_size, void* d_ws, size_t ws_size,
                              hipStream_t stream) {
    const float* r   = (const float*)d_in[0];
    const float* W1  = (const float*)d_in[1];
    const float* b1  = (const float*)d_in[2];
    const float* W2  = (const float*)d_in[3];
    const float* b2  = (const float*)d_in[4];
    const float* wl0 = (const float*)d_in[5];
    const float* wl1 = (const float*)d_in[6];
    float* out = (float*)d_out;

    unsigned short* w2hs = (unsigned short*)d_ws;                 // 196608 bf16
    unsigned short* w2ls = w2hs + (size_t)MULD * HID;             // 196608 bf16

    prep_w2s<<<(MULD * HID) / 256, 256, 0, stream>>>(W2, w2hs, w2ls);

    const int nblocks = E_TOTAL / G;   // 625
    fused_tp_kernel<<<nblocks, BLK, 0, stream>>>(r, W1, b1, w2hs, w2ls, b2, wl0, wl1, out);
}

// Round 14
// 98.073 us; speedup vs baseline: 4.2260x; 1.1770x over previous
//
#include <hip/hip_runtime.h>
#include <math.h>

#define E_TOTAL 20000
#define G 16           // edges per block (1 MFMA edge-group)
#define BLK 256        // 4 waves
#define NB 64
#define HID 128
#define MULD 1536

typedef float f32x4 __attribute__((ext_vector_type(4)));
typedef short bf16x8 __attribute__((ext_vector_type(8)));

struct f3_t { float x, y, z; };   // 12-byte store -> global_store_dwordx3

static __device__ __forceinline__ unsigned short f2bf(float f) {
    unsigned int u = __float_as_uint(f);
    unsigned int r = u + 0x7FFFu + ((u >> 16) & 1u);
    return (unsigned short)(r >> 16);
}
static __device__ __forceinline__ float bf2f(unsigned short h) {
    return __uint_as_float(((unsigned int)h) << 16);
}

// ---------------- prep: W2 [128][1536] fp32 -> swizzled hi/lo bf16 ----------------
// slot layout: flat index i = ((ntg*4 + kk)*64 + lane)*8 + j
// content: W2t[n = ntg*16 + (lane&15)][k = kk*32 + (lane>>4)*8 + j] = W2[k][n]
__global__ __launch_bounds__(256) void prep_w2s(const float* __restrict__ W2,
                                                unsigned short* __restrict__ hi,
                                                unsigned short* __restrict__ lo) {
    const int i = blockIdx.x * 256 + threadIdx.x;   // 0 .. 196607
    const int j    = i & 7;
    const int lane = (i >> 3) & 63;
    const int kk   = (i >> 9) & 3;
    const int ntg  = i >> 11;                        // 0..95
    const int k = kk*32 + (lane >> 4)*8 + j;
    const int n = ntg*16 + (lane & 15);
    const float f = W2[k * MULD + n];
    const unsigned short h = f2bf(f);
    hi[i] = h;
    lo[i] = f2bf(f - bf2f(h));
}

// ---------------- main fused kernel ----------------
__global__ __launch_bounds__(BLK) void fused_tp_kernel(
    const float* __restrict__ r,
    const float* __restrict__ W1,
    const float* __restrict__ b1,
    const unsigned short* __restrict__ w2hs,  // swizzled hi
    const unsigned short* __restrict__ w2ls,  // swizzled lo
    const float* __restrict__ b2,
    const float* __restrict__ wl0,
    const float* __restrict__ wl1,
    float* __restrict__ out)
{
    __shared__ __align__(16) float s_h[G][132];     // h fp32, padded
    __shared__ __align__(16) float s_basis[G][NB];
    __shared__ __align__(16) float s_b2[MULD];
    __shared__ float s_Y1[G][3];
    __shared__ float s_A1[G][9];
    __shared__ float s_A2[G][9];
    __shared__ float s_rad[G];
    __shared__ int   s_mask[G];

    const int t  = threadIdx.x;
    const int e0 = blockIdx.x * G;
    const int w  = t >> 6;        // wave id 0..3
    const int l  = t & 63;
    const int lr = l & 15;
    const int lq = l >> 4;

    // ---------------- Phase A: geometry ----------------
    if (t < G) {
        const int e = e0 + t;
        float rx = r[e*3+0], ry = r[e*3+1], rz = r[e*3+2];
        float rad = sqrtf(rx*rx + ry*ry + rz*rz);
        s_rad[t]  = rad;
        s_mask[t] = (rad > 0.0f) ? 1 : 0;
        float inv = 1.0f / fmaxf(rad, 1e-12f);
        float x = rx*inv, y = ry*inv, z = rz*inv;

        const float SQ3  = 1.7320508075688772f;
        const float SQ15 = 3.872983346207417f;
        float Y10 = SQ3*y, Y11 = SQ3*z, Y12 = SQ3*x;
        s_Y1[t][0]=Y10; s_Y1[t][1]=Y11; s_Y1[t][2]=Y12;

        float Y20 = SQ15*x*y;
        float Y21 = SQ15*y*z;
        float Y22 = 1.118033988749895f*(3.f*z*z - 1.f);
        float Y23 = SQ15*z*x;
        float Y24 = 1.9364916731037085f*(x*x - y*y);

        const float n1  = 0.21650635094610965f;  // sqrt(3)/8
        const float r6  = 0.4082482904638631f;
        const float cA1 = n1 * r6;
        s_A1[t][0] = 0.0f;      s_A1[t][1] =  cA1*Y12; s_A1[t][2] = -cA1*Y11;
        s_A1[t][3] = -cA1*Y12;  s_A1[t][4] = 0.0f;     s_A1[t][5] =  cA1*Y10;
        s_A1[t][6] =  cA1*Y11;  s_A1[t][7] = -cA1*Y10; s_A1[t][8] = 0.0f;

        const float s2 = 0.7071067811865476f;
        float M00 = -r6*Y22 + s2*Y24;
        float M01 =  s2*Y20;
        float M02 =  s2*Y23;
        float M11 = -r6*Y22 - s2*Y24;
        float M12 =  s2*Y21;
        float M22 =  2.0f*r6*Y22;
        const float c5 = n1 * 0.4472135954999579f;
        s_A2[t][0] = c5*M11; s_A2[t][1] = c5*M12; s_A2[t][2] = c5*M01;
        s_A2[t][3] = c5*M12; s_A2[t][4] = c5*M22; s_A2[t][5] = c5*M02;
        s_A2[t][6] = c5*M01; s_A2[t][7] = c5*M02; s_A2[t][8] = c5*M00;
    }
    __syncthreads();

    // ---------------- Phase B: RBF + b2 staging ----------------
    for (int idx = t; idx < G*NB; idx += BLK) {
        int g = idx >> 6, k = idx & 63;
        float rad = s_rad[g];
        float c = (3.0f * (float)k) * (1.0f/63.0f);
        float d = (rad - c) * (64.0f/3.0f);
        s_basis[g][k] = __expf(-d*d);
    }
    for (int idx = t; idx < MULD; idx += BLK) s_b2[idx] = b2[idx];
    __syncthreads();

    // ---------------- Phase C: h = silu(basis@W1+b1), f32x4 per item ----------------
    for (int idx = t; idx < G*32; idx += BLK) {      // 512 f32x4 items
        const int g  = idx >> 5;
        const int c0 = (idx & 31) * 4;
        f32x4 acc = *reinterpret_cast<const f32x4*>(&b1[c0]);
#pragma unroll 8
        for (int k = 0; k < NB; ++k) {
            const f32x4 wv = *reinterpret_cast<const f32x4*>(&W1[k*HID + c0]);
            const float bv = s_basis[g][k];
            acc.x = fmaf(bv, wv.x, acc.x);
            acc.y = fmaf(bv, wv.y, acc.y);
            acc.z = fmaf(bv, wv.z, acc.z);
            acc.w = fmaf(bv, wv.w, acc.w);
        }
        f32x4 res;
        res.x = acc.x / (1.0f + __expf(-acc.x));
        res.y = acc.y / (1.0f + __expf(-acc.y));
        res.z = acc.z / (1.0f + __expf(-acc.z));
        res.w = acc.w / (1.0f + __expf(-acc.w));
        *reinterpret_cast<f32x4*>(&s_h[g][c0]) = res;
    }
    __syncthreads();

    // ---------------- A-fragments (hi/lo bf16), one edge group ----------------
    bf16x8 ah[4], al[4];
    {
        const float* hrow = &s_h[lr][0];
#pragma unroll
        for (int kk = 0; kk < 4; ++kk) {
            f32x4 v0 = *reinterpret_cast<const f32x4*>(&hrow[kk*32 + lq*8]);
            f32x4 v1 = *reinterpret_cast<const f32x4*>(&hrow[kk*32 + lq*8 + 4]);
            float hv[8] = {v0.x, v0.y, v0.z, v0.w, v1.x, v1.y, v1.z, v1.w};
            bf16x8 h8, l8;
#pragma unroll
            for (int j = 0; j < 8; ++j) {
                unsigned short hb = f2bf(hv[j]);
                float rem = hv[j] - bf2f(hb);
                h8[j] = (short)hb;
                l8[j] = (short)f2bf(rem);
            }
            ah[kk] = h8; al[kk] = l8;
        }
    }

    const float c00 = 0.17677669529663687f;   // 1/sqrt(32)
    const float cTR = 0.10206207261596577f;   // c00/sqrt(3)
    const float cBL = 0.125f;
    const float cD  = 0.125f;

    const bf16x8* ph = reinterpret_cast<const bf16x8*>(w2hs);
    const bf16x8* pl = reinterpret_cast<const bf16x8*>(w2ls);

    // proven store bodies, edge = 4lq + rr
    auto store_single = [&](f32x4 acc, int p, int nt) {
        if (p == 0) {
#pragma unroll
            for (int rr = 0; rr < 4; ++rr) {
                int e = lq*4 + rr;
                float v = c00 * acc[rr];
                __builtin_nontemporal_store(v, &out[(size_t)(e0+e)*4096 + nt*64 + lr]);
            }
        } else if (p == 1) {
#pragma unroll
            for (int rr = 0; rr < 4; ++rr) {
                int e = lq*4 + rr;
                float base = cBL * acc[rr];
#pragma unroll
                for (int a = 0; a < 3; ++a) {
                    float v = base * s_Y1[e][a];
                    __builtin_nontemporal_store(v, &out[(size_t)(e0+e)*4096 + (16 + nt*3 + a)*64 + lr]);
                }
            }
        } else {
            // TR: lane lr owns cols 16+3lr..16+3lr+2 -> one 12B store
#pragma unroll
            for (int rr = 0; rr < 4; ++rr) {
                int e = lq*4 + rr;
                float base = cTR * acc[rr];
                f3_t v = { base * s_Y1[e][0], base * s_Y1[e][1], base * s_Y1[e][2] };
                *reinterpret_cast<f3_t*>(&out[(size_t)(e0+e)*4096 + nt*64 + 16 + lr*3]) = v;
            }
        }
    };

    auto store_triple = [&](f32x4 a3, f32x4 a4, f32x4 a5, int o) {
#pragma unroll
        for (int rr = 0; rr < 4; ++rr) {
            int e = lq*4 + rr;
            const float* A1 = &s_A1[e][0];
            const float* A2 = &s_A2[e][0];
            float rv3 = cD * a3[rr], rv4 = a4[rr], rv5 = a5[rr];
            float* orow = &out[(size_t)(e0+e)*4096 + (16 + o*3)*64 + 16 + lr*3];
#pragma unroll
            for (int a = 0; a < 3; ++a) {
                f3_t v;
                float v0 = fmaf(rv4, A1[a*3+0], rv5 * A2[a*3+0]);
                float v1 = fmaf(rv4, A1[a*3+1], rv5 * A2[a*3+1]);
                float v2 = fmaf(rv4, A1[a*3+2], rv5 * A2[a*3+2]);
                if (a == 0) v0 += rv3;
                if (a == 1) v1 += rv3;
                if (a == 2) v2 += rv3;
                v.x = v0; v.y = v1; v.z = v2;
                *reinterpret_cast<f3_t*>(&orow[a*64]) = v;
            }
        }
    };

    // ---------------- pipelined item loop: 12 singles + 4 triple-groups ----------------
    // singles: ntg = w + 4s (s=0..11); triples: o = w+4u (u=0..3), tiles {48+o,64+o,80+o}
    const int items[24] = {
        w, w+4, w+8, w+12, w+16, w+20, w+24, w+28, w+32, w+36, w+40, w+44,
        48+w,    64+w,    80+w,
        48+w+4,  64+w+4,  80+w+4,
        48+w+8,  64+w+8,  80+w+8,
        48+w+12, 64+w+12, 80+w+12 };

    bf16x8 B0h[4], B0l[4], B1h[4], B1l[4];
    auto loadB = [&](bf16x8* Bh, bf16x8* Bl, int ntg) {
#pragma unroll
        for (int kk = 0; kk < 4; ++kk) {
            Bh[kk] = ph[(ntg*4 + kk)*64 + l];
            Bl[kk] = pl[(ntg*4 + kk)*64 + l];
        }
    };
    auto mfma_item = [&](const bf16x8* Bh, const bf16x8* Bl, int ntg) -> f32x4 {
        const float b2v = s_b2[ntg*16 + lr];
        f32x4 a = f32x4{b2v, b2v, b2v, b2v};
#pragma unroll
        for (int kk = 0; kk < 4; ++kk) {
            a = __builtin_amdgcn_mfma_f32_16x16x32_bf16(ah[kk], Bh[kk], a, 0, 0, 0);
            a = __builtin_amdgcn_mfma_f32_16x16x32_bf16(ah[kk], Bl[kk], a, 0, 0, 0);
            a = __builtin_amdgcn_mfma_f32_16x16x32_bf16(al[kk], Bh[kk], a, 0, 0, 0);
        }
        return a;
    };

    loadB(B0h, B0l, items[0]);
    f32x4 tri[3];

#pragma unroll
    for (int i = 0; i < 24; ++i) {
        bf16x8* curH = (i & 1) ? B1h : B0h;
        bf16x8* curL = (i & 1) ? B1l : B0l;
        bf16x8* nxtH = (i & 1) ? B0h : B1h;
        bf16x8* nxtL = (i & 1) ? B0l : B1l;
        if (i < 23) loadB(nxtH, nxtL, items[i+1]);   // prefetch next item

        f32x4 a = mfma_item(curH, curL, items[i]);

        if (i < 12) {
            const int p  = items[i] >> 4;
            const int nt = items[i] & 15;
            store_single(a, p, nt);
        } else {
            const int ti = (i - 12) % 3;
            tri[ti] = a;
            if (ti == 2) {
                const int o = w + ((i - 12) / 3) * 4;
                store_triple(tri[0], tri[1], tri[2], o);
            }
        }
    }

    // ---------------- fixup: masked edges get kernel2 ----------------
    bool any = false;
#pragma unroll
    for (int e = 0; e < G; ++e) any |= (s_mask[e] == 0);
    if (any) {
        __syncthreads();
        for (int idx = t; idx < G*1024; idx += BLK) {
            int e = idx >> 10;
            if (s_mask[e]) continue;
            int q = idx & 1023;
            int row = q >> 4, col = (q & 15) * 4;
            float v[4];
#pragma unroll
            for (int j = 0; j < 4; ++j) {
                int cl = col + j;
                float val = 0.0f;
                if (row < 16 && cl < 16) {
                    val = wl0[row*16 + cl] * 0.25f;
                } else if (row >= 16 && cl >= 16) {
                    int o = (row-16)/3, aa = (row-16)%3;
                    int i2 = (cl-16)/3, bb = (cl-16)%3;
                    val = (aa == bb) ? wl1[o*16 + i2] * 0.25f : 0.0f;
                }
                v[j] = val;
            }
            f32x4 pack = {v[0], v[1], v[2], v[3]};
            __builtin_nontemporal_store(pack,
                reinterpret_cast<f32x4*>(&out[(size_t)(e0+e)*4096 + row*64 + col]));
        }
    }
}

extern "C" void kernel_launch(void* const* d_in, const int* in_sizes, int n_in,
                              void* d_out, int out_size, void* d_ws, size_t ws_size,
                              hipStream_t stream) {
    const float* r   = (const float*)d_in[0];
    const float* W1  = (const float*)d_in[1];
    const float* b1  = (const float*)d_in[2];
    const float* W2  = (const float*)d_in[3];
    const float* b2  = (const float*)d_in[4];
    const float* wl0 = (const float*)d_in[5];
    const float* wl1 = (const float*)d_in[6];
    float* out = (float*)d_out;

    unsigned short* w2hs = (unsigned short*)d_ws;                 // 196608 bf16
    unsigned short* w2ls = w2hs + (size_t)MULD * HID;             // 196608 bf16

    prep_w2s<<<(MULD * HID) / 256, 256, 0, stream>>>(W2, w2hs, w2ls);

    const int nblocks = E_TOTAL / G;   // 1250
    fused_tp_kernel<<<nblocks, BLK, 0, stream>>>(r, W1, b1, w2hs, w2ls, b2, wl0, wl1, out);
}